// Round 1
// baseline (553.367 us; speedup 1.0000x reference)
//
#include <hip/hip_runtime.h>
#include <hip/hip_bf16.h>

#define SLEN   4096
#define HDIM   768
#define NHEADS 12
#define HEADD  64
#define NQKV   2304
#define WIN    64

constexpr float SCALE = 0.125f;  // 64^-0.5
constexpr float LOG2E = 1.4426950408889634f;

// C = A(MxK) * B(NxK)^T, fp32, BM=128, BK=16, 256 threads, micro-tile 8 x (BN/16),
// thread cols strided by 16 so each thread holds RoPE pairs (d, d+32).
// MODE 0: plain row-major C[M][N] write.
// MODE 1: QKV epilogue — RoPE on q/k panels, scatter to QKV[3][NH][S][64].
template <int BN, int MODE>
__global__ __launch_bounds__(256) void gemm_bt(
    const float* __restrict__ A, const float* __restrict__ B,
    float* __restrict__ C, int M, int N, int K,
    const float* __restrict__ cosT, const float* __restrict__ sinT)
{
    constexpr int BM = 128, BK = 16;
    constexpr int TN = BN / 16;
    __shared__ float As[BK][BM + 4];
    __shared__ float Bs[BK][BN + 4];

    const int tid = threadIdx.x;
    const int tx = tid & 15;
    const int ty = tid >> 4;
    const int rowBase = blockIdx.y * BM;
    const int colBase = blockIdx.x * BN;

    float acc[8][TN];
#pragma unroll
    for (int i = 0; i < 8; ++i)
#pragma unroll
        for (int j = 0; j < TN; ++j) acc[i][j] = 0.f;

    for (int k0 = 0; k0 < K; k0 += BK) {
        // A tile: BM x BK (transposed store As[k][row])
#pragma unroll
        for (int r = 0; r < (BM * BK) / (4 * 256); ++r) {
            int idx = tid + 256 * r;
            int row = idx >> 2;   // 4 float4 per row (BK=16)
            int c4  = idx & 3;
            float4 v = *reinterpret_cast<const float4*>(
                &A[(size_t)(rowBase + row) * K + k0 + c4 * 4]);
            As[c4 * 4 + 0][row] = v.x;
            As[c4 * 4 + 1][row] = v.y;
            As[c4 * 4 + 2][row] = v.z;
            As[c4 * 4 + 3][row] = v.w;
        }
        // B tile: BN x BK
#pragma unroll
        for (int r = 0; r < (BN * BK) / (4 * 256); ++r) {
            int idx = tid + 256 * r;
            int row = idx >> 2;
            int c4  = idx & 3;
            float4 v = *reinterpret_cast<const float4*>(
                &B[(size_t)(colBase + row) * K + k0 + c4 * 4]);
            Bs[c4 * 4 + 0][row] = v.x;
            Bs[c4 * 4 + 1][row] = v.y;
            Bs[c4 * 4 + 2][row] = v.z;
            Bs[c4 * 4 + 3][row] = v.w;
        }
        __syncthreads();
#pragma unroll
        for (int kk = 0; kk < BK; ++kk) {
            float a[8], b[TN];
#pragma unroll
            for (int i = 0; i < 8; ++i) a[i] = As[kk][ty * 8 + i];
#pragma unroll
            for (int j = 0; j < TN; ++j) b[j] = Bs[kk][tx + 16 * j];
#pragma unroll
            for (int i = 0; i < 8; ++i)
#pragma unroll
                for (int j = 0; j < TN; ++j) acc[i][j] += a[i] * b[j];
        }
        __syncthreads();
    }

    if constexpr (MODE == 0) {
#pragma unroll
        for (int i = 0; i < 8; ++i) {
            int row = rowBase + ty * 8 + i;
#pragma unroll
            for (int j = 0; j < TN; ++j)
                C[(size_t)row * N + colBase + tx + 16 * j] = acc[i][j];
        }
    } else {
        // TN == 8 here. Pairs: j in {0,1,4,5} pairs with j+2 (d and d+32 of a head).
#pragma unroll
        for (int i = 0; i < 8; ++i) {
            int srow = rowBase + ty * 8 + i;
#pragma unroll
            for (int jp = 0; jp < 4; ++jp) {
                int j = (jp & 1) + (jp >> 1) * 4;  // {0,1,4,5}
                int col = colBase + tx + 16 * j;
                int t_idx = col / HDIM;            // 0=q,1=k,2=v
                int rem = col - t_idx * HDIM;
                int h = rem >> 6;
                int dlo = rem & 63;                // guaranteed < 32
                float lo = acc[i][j];
                float hi = acc[i][j + 2];
                float* dst = C + (((size_t)t_idx * NHEADS + h) * SLEN + srow) * HEADD;
                if (t_idx < 2) {
                    float c  = cosT[srow * HEADD + dlo];
                    float sn = sinT[srow * HEADD + dlo];
                    float nlo = lo * c - hi * sn;
                    float nhi = hi * c + lo * sn;
                    dst[dlo]      = nlo;
                    dst[dlo + 32] = nhi;
                } else {
                    dst[dlo]      = lo;
                    dst[dlo + 32] = hi;
                }
            }
        }
    }
}

// Sliding-window causal attention. Block = (head, 64-query tile); 256 threads = 4 waves,
// each wave owns 16 queries. K/V window tile (128 rows) + Q tile staged in LDS.
// Scores: lane = key (<=65 keys; 65th handled cooperatively). PV: lane = dim.
__global__ __launch_bounds__(256) void attn_swa(
    const float* __restrict__ QKV, float* __restrict__ O)
{
    const int h  = blockIdx.x >> 6;
    const int qt = blockIdx.x & 63;
    const int qbase = qt << 6;
    const int kbase = qbase - 64;

    __shared__ float Qs[64][65];
    __shared__ float Ks[128][65];
    __shared__ float Vs[128][65];
    __shared__ float Ps[4][66];

    const float* Qg = QKV + ((size_t)(0 * NHEADS + h) * SLEN) * HEADD;
    const float* Kg = QKV + ((size_t)(1 * NHEADS + h) * SLEN) * HEADD;
    const float* Vg = QKV + ((size_t)(2 * NHEADS + h) * SLEN) * HEADD;

    const int tid = threadIdx.x;
#pragma unroll
    for (int r = 0; r < 8; ++r) {       // K/V: 128 rows x 64 floats = 2048 float4 each
        int idx = tid + 256 * r;
        int row = idx >> 4;
        int c4  = idx & 15;
        int gr  = kbase + row;
        int grc = gr < 0 ? 0 : gr;      // clamped rows are never read
        float4 kv = *reinterpret_cast<const float4*>(&Kg[(size_t)grc * HEADD + c4 * 4]);
        float4 vv = *reinterpret_cast<const float4*>(&Vg[(size_t)grc * HEADD + c4 * 4]);
        Ks[row][c4 * 4 + 0] = kv.x; Ks[row][c4 * 4 + 1] = kv.y;
        Ks[row][c4 * 4 + 2] = kv.z; Ks[row][c4 * 4 + 3] = kv.w;
        Vs[row][c4 * 4 + 0] = vv.x; Vs[row][c4 * 4 + 1] = vv.y;
        Vs[row][c4 * 4 + 2] = vv.z; Vs[row][c4 * 4 + 3] = vv.w;
    }
#pragma unroll
    for (int r = 0; r < 4; ++r) {       // Q: 64 rows x 64 floats
        int idx = tid + 256 * r;
        int row = idx >> 4;
        int c4  = idx & 15;
        float4 qv = *reinterpret_cast<const float4*>(&Qg[(size_t)(qbase + row) * HEADD + c4 * 4]);
        Qs[row][c4 * 4 + 0] = qv.x; Qs[row][c4 * 4 + 1] = qv.y;
        Qs[row][c4 * 4 + 2] = qv.z; Qs[row][c4 * 4 + 3] = qv.w;
    }
    __syncthreads();

    const int wave = tid >> 6;
    const int lane = tid & 63;

    for (int n = 0; n < 16; ++n) {
        int qi   = wave * 16 + n;
        int srow = qbase + qi;
        int jlo  = srow - WIN; if (jlo < 0) jlo = 0;
        int nk   = srow - jlo + 1;      // <= 65
        int kjlo = jlo - kbase;         // local key base in tile

        // phase A: lane l scores key kjlo+l (l < min(nk,64))
        float sc = -1e30f;
        if (lane < nk) {
            int kj = kjlo + lane;
            float d0 = 0.f;
#pragma unroll
            for (int d = 0; d < HEADD; ++d) d0 += Qs[qi][d] * Ks[kj][d];
            sc = d0 * SCALE;
        }
        // phase B: 65th key handled by full-wave reduce
        float sc65 = -1e30f;
        if (nk == 65) {
            int kj = kjlo + 64;
            float p = Qs[qi][lane] * Ks[kj][lane];
#pragma unroll
            for (int off = 32; off >= 1; off >>= 1) p += __shfl_xor(p, off);
            sc65 = p * SCALE;
        }
        // softmax
        float m = sc;
#pragma unroll
        for (int off = 32; off >= 1; off >>= 1) m = fmaxf(m, __shfl_xor(m, off));
        m = fmaxf(m, sc65);
        float p = exp2f((sc - m) * LOG2E);   // invalid lanes: sc=-1e30 -> 0
        float lsum = p;
#pragma unroll
        for (int off = 32; off >= 1; off >>= 1) lsum += __shfl_xor(lsum, off);
        float p65 = (nk == 65) ? exp2f((sc65 - m) * LOG2E) : 0.f;
        lsum += p65;

        Ps[wave][lane] = p;
        if (lane == 0) Ps[wave][64] = p65;
        __syncthreads();   // uniform across block (all waves run 16 iters)

        // PV: lane = output dim
        float o = 0.f;
        for (int kk = 0; kk < nk; ++kk) {
            float pv = Ps[wave][kk];
            o += pv * Vs[kjlo + kk][lane];
        }
        o /= lsum;
        O[(size_t)srow * HDIM + h * HEADD + lane] = o;
        __syncthreads();
    }
}

extern "C" void kernel_launch(void* const* d_in, const int* in_sizes, int n_in,
                              void* d_out, int out_size, void* d_ws, size_t ws_size,
                              hipStream_t stream)
{
    const float* hs   = (const float*)d_in[0];
    const float* wqkv = (const float*)d_in[1];
    const float* wo   = (const float*)d_in[2];
    const float* cosT = (const float*)d_in[3];
    const float* sinT = (const float*)d_in[4];
    // d_in[5] attention_mask: unused (mask applied analytically)
    float* out = (float*)d_out;

    float* qkvw = (float*)d_ws;                                  // [3][12][4096][64] f32
    float* ow   = qkvw + (size_t)3 * NHEADS * SLEN * HEADD;      // [4096][768] f32

    dim3 g1(NQKV / 128, SLEN / 128);
    gemm_bt<128, 1><<<g1, 256, 0, stream>>>(hs, wqkv, qkvw, SLEN, NQKV, HDIM, cosT, sinT);

    attn_swa<<<NHEADS * (SLEN / 64), 256, 0, stream>>>(qkvw, ow);

    dim3 g2(HDIM / 64, SLEN / 128);
    gemm_bt<64, 0><<<g2, 256, 0, stream>>>(ow, wo, out, SLEN, HDIM, HDIM, nullptr, nullptr);
}

// Round 3
// 383.946 us; speedup vs baseline: 1.4413x; 1.4413x over previous
//
#include <hip/hip_runtime.h>

#define SLEN   4096
#define HDIM   768
#define NHEADS 12
#define HEADD  64
#define NQKV   2304
#define WIN    64

constexpr float SCALE = 0.125f;  // 64^-0.5
constexpr float LOG2E = 1.4426950408889634f;

typedef short bf16x8 __attribute__((ext_vector_type(8)));
typedef float f32x4  __attribute__((ext_vector_type(4)));

// ---- bf16 split helpers: x ~= hi + lo, each bf16 (RN). Packed u32 = hi | lo<<16.
__device__ inline unsigned short f2bf(float x) {
    unsigned u = __float_as_uint(x);
    u += 0x7fff + ((u >> 16) & 1);
    return (unsigned short)(u >> 16);
}
__device__ inline float bf2f(unsigned short b) { return __uint_as_float(((unsigned)b) << 16); }
__device__ inline unsigned packsplit(float x) {
    unsigned short h = f2bf(x);
    unsigned short l = f2bf(x - bf2f(h));
    return (unsigned)h | ((unsigned)l << 16);
}
__device__ inline float unpackf(unsigned u) {
    return __uint_as_float(u << 16) + __uint_as_float(u & 0xffff0000u);
}

// XOR swizzle on 16B units within a 64B LDS row (breaks ds_read_b128 bank conflicts)
__device__ inline int swzb(int row, int bir) {
    return row * 64 + (((bir & 48) ^ ((row & 3) << 4)) | (bir & 15));
}

// C = A(MxK) * B(NxK)^T via split-bf16 MFMA. BM=BN=128, BK=32, 256 thr = 4 waves (2x2),
// each wave 64x64 out = 4x4 frags of 16x16, 3 MFMAs per frag pair (hihi+hilo+lohi).
// ASRC/BSRC: 0 = fp32 global, 1 = packed u32 (hi|lo) global.
// MODE 0: fp32 row-major C. MODE 1: QKV epilogue — RoPE on q/k, packed-u32 scatter.
template <int MODE, int ASRC, int BSRC>
__global__ __launch_bounds__(256) void gemm_mfma(
    const void* __restrict__ Av, const void* __restrict__ Bv, void* __restrict__ Cv,
    int M, int N, int K, const float* __restrict__ cosT, const float* __restrict__ sinT)
{
    constexpr int BM = 128, BN = 128, BK = 32;
    __shared__ unsigned short sAhi[BM * BK], sAlo[BM * BK];
    __shared__ unsigned short sBhi[BN * BK], sBlo[BN * BK];

    const int tid = threadIdx.x;
    const int wid = tid >> 6, lane = tid & 63;
    const int wr = wid >> 1, wc = wid & 1;
    const int l15 = lane & 15, l4 = lane >> 4;
    const int rowBase = blockIdx.y * BM, colBase = blockIdx.x * BN;

    f32x4 acc[4][4];
#pragma unroll
    for (int m = 0; m < 4; ++m)
#pragma unroll
        for (int n = 0; n < 4; ++n) acc[m][n] = f32x4{0.f, 0.f, 0.f, 0.f};

    for (int k0 = 0; k0 < K; k0 += BK) {
        // ---- stage A tile (128x32) and B tile (128x32): 4 elems/thread/iter
#pragma unroll
        for (int r = 0; r < 4; ++r) {
            int idx = tid + 256 * r;
            int row = idx >> 3, c4 = (idx & 7) * 4;
            unsigned short h[4], l[4];
            if constexpr (ASRC == 0) {
                float4 f = *(const float4*)((const float*)Av + (size_t)(rowBase + row) * K + k0 + c4);
                float fv[4] = {f.x, f.y, f.z, f.w};
#pragma unroll
                for (int j = 0; j < 4; ++j) { h[j] = f2bf(fv[j]); l[j] = f2bf(fv[j] - bf2f(h[j])); }
            } else {
                uint4 p = *(const uint4*)((const unsigned*)Av + (size_t)(rowBase + row) * K + k0 + c4);
                unsigned pv[4] = {p.x, p.y, p.z, p.w};
#pragma unroll
                for (int j = 0; j < 4; ++j) { h[j] = (unsigned short)(pv[j] & 0xffff); l[j] = (unsigned short)(pv[j] >> 16); }
            }
            int byte = swzb(row, c4 * 2);
            *(uint2*)((char*)sAhi + byte) = uint2{(unsigned)h[0] | ((unsigned)h[1] << 16), (unsigned)h[2] | ((unsigned)h[3] << 16)};
            *(uint2*)((char*)sAlo + byte) = uint2{(unsigned)l[0] | ((unsigned)l[1] << 16), (unsigned)l[2] | ((unsigned)l[3] << 16)};
        }
#pragma unroll
        for (int r = 0; r < 4; ++r) {
            int idx = tid + 256 * r;
            int row = idx >> 3, c4 = (idx & 7) * 4;
            unsigned short h[4], l[4];
            if constexpr (BSRC == 0) {
                float4 f = *(const float4*)((const float*)Bv + (size_t)(colBase + row) * K + k0 + c4);
                float fv[4] = {f.x, f.y, f.z, f.w};
#pragma unroll
                for (int j = 0; j < 4; ++j) { h[j] = f2bf(fv[j]); l[j] = f2bf(fv[j] - bf2f(h[j])); }
            } else {
                uint4 p = *(const uint4*)((const unsigned*)Bv + (size_t)(colBase + row) * K + k0 + c4);
                unsigned pv[4] = {p.x, p.y, p.z, p.w};
#pragma unroll
                for (int j = 0; j < 4; ++j) { h[j] = (unsigned short)(pv[j] & 0xffff); l[j] = (unsigned short)(pv[j] >> 16); }
            }
            int byte = swzb(row, c4 * 2);
            *(uint2*)((char*)sBhi + byte) = uint2{(unsigned)h[0] | ((unsigned)h[1] << 16), (unsigned)h[2] | ((unsigned)h[3] << 16)};
            *(uint2*)((char*)sBlo + byte) = uint2{(unsigned)l[0] | ((unsigned)l[1] << 16), (unsigned)l[2] | ((unsigned)l[3] << 16)};
        }
        __syncthreads();

        // ---- fragments + MFMA
        bf16x8 ah[4], al[4];
#pragma unroll
        for (int m = 0; m < 4; ++m) {
            int row = wr * 64 + m * 16 + l15;
            int byte = row * 64 + ((l4 * 16) ^ ((row & 3) << 4));
            ah[m] = *(const bf16x8*)((const char*)sAhi + byte);
            al[m] = *(const bf16x8*)((const char*)sAlo + byte);
        }
#pragma unroll
        for (int n = 0; n < 4; ++n) {
            int row = wc * 64 + n * 16 + l15;
            int byte = row * 64 + ((l4 * 16) ^ ((row & 3) << 4));
            bf16x8 bh = *(const bf16x8*)((const char*)sBhi + byte);
            bf16x8 bl = *(const bf16x8*)((const char*)sBlo + byte);
#pragma unroll
            for (int m = 0; m < 4; ++m) {
                acc[m][n] = __builtin_amdgcn_mfma_f32_16x16x32_bf16(ah[m], bh, acc[m][n], 0, 0, 0);
                acc[m][n] = __builtin_amdgcn_mfma_f32_16x16x32_bf16(ah[m], bl, acc[m][n], 0, 0, 0);
                acc[m][n] = __builtin_amdgcn_mfma_f32_16x16x32_bf16(al[m], bh, acc[m][n], 0, 0, 0);
            }
        }
        __syncthreads();
    }

    // ---- epilogue. C/D layout: col = lane&15, row = (lane>>4)*4 + reg  [m89-verified]
    if constexpr (MODE == 0) {
        float* C = (float*)Cv;
#pragma unroll
        for (int m = 0; m < 4; ++m)
#pragma unroll
            for (int n = 0; n < 4; ++n)
#pragma unroll
                for (int j = 0; j < 4; ++j) {
                    int row = rowBase + wr * 64 + m * 16 + l4 * 4 + j;
                    int col = colBase + wc * 64 + n * 16 + l15;
                    C[(size_t)row * N + col] = acc[m][n][j];
                }
    } else {
        // wave's 64-col span = exactly one (tensor, head): RoPE pairs are (n, n+2)
        unsigned* QKVp = (unsigned*)Cv;
        const int span = colBase + wc * 64;
        const int t = span / HDIM;
        const int hh = (span - t * HDIM) >> 6;
        unsigned* dstH = QKVp + (((size_t)t * NHEADS + hh) * SLEN) * HEADD;
#pragma unroll
        for (int m = 0; m < 4; ++m)
#pragma unroll
            for (int np = 0; np < 2; ++np)
#pragma unroll
                for (int j = 0; j < 4; ++j) {
                    int srow = rowBase + wr * 64 + m * 16 + l4 * 4 + j;
                    int dlo = np * 16 + l15;  // < 32
                    float lo = acc[m][np][j];
                    float hi = acc[m][np + 2][j];
                    unsigned* dst = dstH + (size_t)srow * HEADD;
                    if (t < 2) {
                        float c = cosT[srow * HEADD + dlo];
                        float s = sinT[srow * HEADD + dlo];
                        float nlo = lo * c - hi * s;
                        float nhi = hi * c + lo * s;
                        dst[dlo]      = packsplit(nlo);
                        dst[dlo + 32] = packsplit(nhi);
                    } else {
                        dst[dlo]      = packsplit(lo);
                        dst[dlo + 32] = packsplit(hi);
                    }
                }
    }
}

// Sliding-window causal attention over packed-u32 QKV[3][NH][S][64]; writes packed ow.
__global__ __launch_bounds__(256) void attn_swa(
    const unsigned* __restrict__ QKV, unsigned* __restrict__ O)
{
    const int h  = blockIdx.x >> 6;
    const int qt = blockIdx.x & 63;
    const int qbase = qt << 6;
    const int kbase = qbase - 64;

    __shared__ float Qs[64][65];
    __shared__ float Ks[128][65];
    __shared__ float Vs[128][65];
    __shared__ float Ps[4][66];

    const unsigned* Qg = QKV + ((size_t)(0 * NHEADS + h) * SLEN) * HEADD;
    const unsigned* Kg = QKV + ((size_t)(1 * NHEADS + h) * SLEN) * HEADD;
    const unsigned* Vg = QKV + ((size_t)(2 * NHEADS + h) * SLEN) * HEADD;

    const int tid = threadIdx.x;
#pragma unroll
    for (int r = 0; r < 8; ++r) {       // K/V: 128 rows x 64 u32
        int idx = tid + 256 * r;
        int row = idx >> 4;
        int c4  = (idx & 15) * 4;
        int gr  = kbase + row;
        int grc = gr < 0 ? 0 : gr;      // clamped rows are never read
        uint4 kp = *(const uint4*)(&Kg[(size_t)grc * HEADD + c4]);
        uint4 vp = *(const uint4*)(&Vg[(size_t)grc * HEADD + c4]);
        Ks[row][c4 + 0] = unpackf(kp.x); Ks[row][c4 + 1] = unpackf(kp.y);
        Ks[row][c4 + 2] = unpackf(kp.z); Ks[row][c4 + 3] = unpackf(kp.w);
        Vs[row][c4 + 0] = unpackf(vp.x); Vs[row][c4 + 1] = unpackf(vp.y);
        Vs[row][c4 + 2] = unpackf(vp.z); Vs[row][c4 + 3] = unpackf(vp.w);
    }
#pragma unroll
    for (int r = 0; r < 4; ++r) {       // Q: 64 rows x 64 u32
        int idx = tid + 256 * r;
        int row = idx >> 4;
        int c4  = (idx & 15) * 4;
        uint4 qp = *(const uint4*)(&Qg[(size_t)(qbase + row) * HEADD + c4]);
        Qs[row][c4 + 0] = unpackf(qp.x); Qs[row][c4 + 1] = unpackf(qp.y);
        Qs[row][c4 + 2] = unpackf(qp.z); Qs[row][c4 + 3] = unpackf(qp.w);
    }
    __syncthreads();

    const int wave = tid >> 6;
    const int lane = tid & 63;

    for (int n = 0; n < 16; ++n) {
        int qi   = wave * 16 + n;
        int srow = qbase + qi;
        int jlo  = srow - WIN; if (jlo < 0) jlo = 0;
        int nk   = srow - jlo + 1;      // <= 65
        int kjlo = jlo - kbase;

        float sc = -1e30f;
        if (lane < nk) {
            int kj = kjlo + lane;
            float d0 = 0.f;
#pragma unroll
            for (int d = 0; d < HEADD; ++d) d0 += Qs[qi][d] * Ks[kj][d];
            sc = d0 * SCALE;
        }
        float sc65 = -1e30f;
        if (nk == 65) {
            int kj = kjlo + 64;
            float p = Qs[qi][lane] * Ks[kj][lane];
#pragma unroll
            for (int off = 32; off >= 1; off >>= 1) p += __shfl_xor(p, off);
            sc65 = p * SCALE;
        }
        float m = sc;
#pragma unroll
        for (int off = 32; off >= 1; off >>= 1) m = fmaxf(m, __shfl_xor(m, off));
        m = fmaxf(m, sc65);
        float p = exp2f((sc - m) * LOG2E);
        float lsum = p;
#pragma unroll
        for (int off = 32; off >= 1; off >>= 1) lsum += __shfl_xor(lsum, off);
        float p65 = (nk == 65) ? exp2f((sc65 - m) * LOG2E) : 0.f;
        lsum += p65;

        Ps[wave][lane] = p;
        if (lane == 0) Ps[wave][64] = p65;
        __syncthreads();

        float o = 0.f;
        for (int kk = 0; kk < nk; ++kk)
            o += Ps[wave][kk] * Vs[kjlo + kk][lane];
        o /= lsum;
        O[(size_t)srow * HDIM + h * HEADD + lane] = packsplit(o);
        __syncthreads();
    }
}

extern "C" void kernel_launch(void* const* d_in, const int* in_sizes, int n_in,
                              void* d_out, int out_size, void* d_ws, size_t ws_size,
                              hipStream_t stream)
{
    const float* hs   = (const float*)d_in[0];
    const float* wqkv = (const float*)d_in[1];
    const float* wo   = (const float*)d_in[2];
    const float* cosT = (const float*)d_in[3];
    const float* sinT = (const float*)d_in[4];
    // d_in[5] attention_mask: unused (mask applied analytically)
    float* out = (float*)d_out;

    unsigned* qkvP = (unsigned*)d_ws;                            // [3][12][4096][64] u32 = 37.7 MB
    unsigned* owP  = qkvP + (size_t)3 * NHEADS * SLEN * HEADD;   // [4096][768] u32 = 12.6 MB

    dim3 g1(NQKV / 128, SLEN / 128);
    gemm_mfma<1, 0, 0><<<g1, 256, 0, stream>>>(hs, wqkv, qkvP, SLEN, NQKV, HDIM, cosT, sinT);

    attn_swa<<<NHEADS * (SLEN / 64), 256, 0, stream>>>(qkvP, owP);

    dim3 g2(HDIM / 128, SLEN / 128);
    gemm_mfma<0, 1, 0><<<g2, 256, 0, stream>>>(owP, wo, out, SLEN, HDIM, HDIM, nullptr, nullptr);
}

// Round 8
// 248.911 us; speedup vs baseline: 2.2232x; 1.5425x over previous
//
#include <hip/hip_runtime.h>

#define SLEN   4096
#define HDIM   768
#define NHEADS 12
#define HEADD  64
#define NQKV   2304
#define WIN    64

constexpr float SCALE = 0.125f;  // 64^-0.5
constexpr float LOG2E = 1.4426950408889634f;

typedef short bf16x8 __attribute__((ext_vector_type(8)));
typedef float f32x4  __attribute__((ext_vector_type(4)));
typedef unsigned short u16;

#define MFMA(a, b, c) __builtin_amdgcn_mfma_f32_16x16x32_bf16((a), (b), (c), 0, 0, 0)

#define GLDS(gp, lp) __builtin_amdgcn_global_load_lds( \
    (const __attribute__((address_space(1))) unsigned*)(gp), \
    (__attribute__((address_space(3))) unsigned*)(lp), 16, 0, 0)

// ---- bf16 split helpers: x ~= hi + lo, each bf16 (RN). Packed u32 = hi | lo<<16.
__device__ inline u16 f2bf(float x) {
    unsigned u = __float_as_uint(x);
    u += 0x7fff + ((u >> 16) & 1);
    return (u16)(u >> 16);
}
__device__ inline float bf2f(u16 b) { return __uint_as_float(((unsigned)b) << 16); }
__device__ inline unsigned packsplit(float x) {
    u16 h = f2bf(x);
    u16 l = f2bf(x - bf2f(h));
    return (unsigned)h | ((unsigned)l << 16);
}

// ============================================================================
// Pre-pass: split f32 [R][768] into hi/lo bf16 planes with quad-swizzle baked in.
// Plane layout (u16 units): elem (r,k) at r*768 + (k>>5)*32 + (((k>>3)&3)^(r&3))*8 + (k&7)
// -> GEMM stages 128x32 tiles via global_load_lds with LINEAR dest; frag ds_reads
//    apply quad XOR (row&3) -> ~2-way bank conflicts (free).
// ============================================================================
__global__ __launch_bounds__(256) void split_planes(
    const float* __restrict__ hs, const float* __restrict__ wq, const float* __restrict__ wo,
    u16* __restrict__ hsH, u16* __restrict__ hsL,
    u16* __restrict__ wqH, u16* __restrict__ wqL,
    u16* __restrict__ woH, u16* __restrict__ woL)
{
    int qid = blockIdx.x * 256 + threadIdx.x;   // one 8-elem quad per thread
    const float* src; u16 *dH, *dL; int r, k8;
    if (qid < 393216)      { src = hs; dH = hsH; dL = hsL; r = qid / 96; k8 = qid % 96; }
    else if (qid < 614400) { int q = qid - 393216; src = wq; dH = wqH; dL = wqL; r = q / 96; k8 = q % 96; }
    else                   { int q = qid - 614400; src = wo; dH = woH; dL = woL; r = q / 96; k8 = q % 96; }

    const float* p = src + (size_t)r * 768 + k8 * 8;
    float4 f0 = *(const float4*)p, f1 = *(const float4*)(p + 4);
    float fv[8] = {f0.x, f0.y, f0.z, f0.w, f1.x, f1.y, f1.z, f1.w};
    unsigned hh[4], ll[4];
#pragma unroll
    for (int i = 0; i < 4; ++i) {
        u16 h0 = f2bf(fv[2*i]),   h1 = f2bf(fv[2*i+1]);
        u16 l0 = f2bf(fv[2*i] - bf2f(h0)), l1 = f2bf(fv[2*i+1] - bf2f(h1));
        hh[i] = (unsigned)h0 | ((unsigned)h1 << 16);
        ll[i] = (unsigned)l0 | ((unsigned)l1 << 16);
    }
    size_t di = (size_t)r * 768 + (k8 >> 2) * 32 + (size_t)(((k8 & 3) ^ (r & 3))) * 8;
    *(uint4*)(dH + di) = uint4{hh[0], hh[1], hh[2], hh[3]};
    *(uint4*)(dL + di) = uint4{ll[0], ll[1], ll[2], ll[3]};
}

// ============================================================================
// GEMM: C = A(MxK) * B(NxK)^T, inputs = swizzled hi/lo planes, split-bf16 (3 MFMA).
// BM=BN=128, BK=32, 256 thr = 4 waves (2x2). Staging: global_load_lds, zero VALU.
// MODE 0: fp32 row-major C. MODE 1: QKV epilogue (RoPE, packed-u32 scatter).
// ============================================================================
template <int MODE>
__global__ __launch_bounds__(256) void gemm_sp(
    const u16* __restrict__ Ah, const u16* __restrict__ Al,
    const u16* __restrict__ Bh, const u16* __restrict__ Bl,
    void* __restrict__ Cv, int M, int N, int K,
    const float* __restrict__ cosT, const float* __restrict__ sinT)
{
    __shared__ u16 sAh[4096], sAl[4096], sBh[4096], sBl[4096];  // 128x32 each, 8KB

    const int tid = threadIdx.x;
    const int w = tid >> 6, lane = tid & 63;
    const int wr = w >> 1, wc = w & 1;
    const int l15 = lane & 15, l4 = lane >> 4;
    const int rowBase = blockIdx.y * 128, colBase = blockIdx.x * 128;
    const size_t strB = (size_t)K * 2;  // plane row stride in bytes

    const char* Ahb = (const char*)Ah; const char* Alb = (const char*)Al;
    const char* Bhb = (const char*)Bh; const char* Blb = (const char*)Bl;

    f32x4 acc[4][4];
#pragma unroll
    for (int m = 0; m < 4; ++m)
#pragma unroll
        for (int n = 0; n < 4; ++n) acc[m][n] = f32x4{0.f, 0.f, 0.f, 0.f};

    const int nkt = K >> 5;
    for (int kt = 0; kt < nkt; ++kt) {
        // stage 4 planes x 8KB; lane's 16B: row = i*64+w*16+(lane>>2), quad = lane&3
#pragma unroll
        for (int i = 0; i < 2; ++i) {
            int row  = i * 64 + w * 16 + (lane >> 2);
            int quad = lane & 3;
            size_t goA = (size_t)(rowBase + row) * strB + kt * 64 + quad * 16;
            size_t goB = (size_t)(colBase + row) * strB + kt * 64 + quad * 16;
            unsigned lo = i * 4096 + w * 1024;
            GLDS(Ahb + goA, (char*)sAh + lo);
            GLDS(Alb + goA, (char*)sAl + lo);
            GLDS(Bhb + goB, (char*)sBh + lo);
            GLDS(Blb + goB, (char*)sBl + lo);
        }
        __syncthreads();

        bf16x8 ah[4], al[4];
#pragma unroll
        for (int m = 0; m < 4; ++m) {
            int row = wr * 64 + m * 16 + l15;
            int byt = row * 64 + ((l4 * 16) ^ ((row & 3) << 4));
            ah[m] = *(const bf16x8*)((const char*)sAh + byt);
            al[m] = *(const bf16x8*)((const char*)sAl + byt);
        }
#pragma unroll
        for (int n = 0; n < 4; ++n) {
            int row = wc * 64 + n * 16 + l15;
            int byt = row * 64 + ((l4 * 16) ^ ((row & 3) << 4));
            bf16x8 bh = *(const bf16x8*)((const char*)sBh + byt);
            bf16x8 bl = *(const bf16x8*)((const char*)sBl + byt);
#pragma unroll
            for (int m = 0; m < 4; ++m) {
                acc[m][n] = MFMA(ah[m], bh, acc[m][n]);
                acc[m][n] = MFMA(ah[m], bl, acc[m][n]);
                acc[m][n] = MFMA(al[m], bh, acc[m][n]);
            }
        }
        __syncthreads();
    }

    // C/D layout: col = lane&15, row = (lane>>4)*4 + reg  [HW-validated round 3]
    if constexpr (MODE == 0) {
        float* C = (float*)Cv;
#pragma unroll
        for (int m = 0; m < 4; ++m)
#pragma unroll
            for (int n = 0; n < 4; ++n)
#pragma unroll
                for (int j = 0; j < 4; ++j) {
                    int row = rowBase + wr * 64 + m * 16 + l4 * 4 + j;
                    int col = colBase + wc * 64 + n * 16 + l15;
                    C[(size_t)row * N + col] = acc[m][n][j];
                }
    } else {
        // wave's 64-col span = one (tensor, head); RoPE pairs (n, n+2)
        unsigned* QKVp = (unsigned*)Cv;
        const int span = colBase + wc * 64;
        const int t = span / HDIM;
        const int hh = (span - t * HDIM) >> 6;
        unsigned* dstH = QKVp + (((size_t)t * NHEADS + hh) * SLEN) * HEADD;
#pragma unroll
        for (int m = 0; m < 4; ++m)
#pragma unroll
            for (int np = 0; np < 2; ++np)
#pragma unroll
                for (int j = 0; j < 4; ++j) {
                    int srow = rowBase + wr * 64 + m * 16 + l4 * 4 + j;
                    int dlo = np * 16 + l15;  // < 32
                    float lo = acc[m][np][j];
                    float hi = acc[m][np + 2][j];
                    unsigned* dst = dstH + (size_t)srow * HEADD;
                    if (t < 2) {
                        float c = cosT[srow * HEADD + dlo];
                        float s = sinT[srow * HEADD + dlo];
                        float nlo = lo * c - hi * s;
                        float nhi = hi * c + lo * s;
                        dst[dlo]      = packsplit(nlo);
                        dst[dlo + 32] = packsplit(nhi);
                    } else {
                        dst[dlo]      = packsplit(lo);
                        dst[dlo + 32] = packsplit(hi);
                    }
                }
    }
}

// ============================================================================
// MFMA sliding-window attention. Block = (head, 64-query tile), 256 thr = 4 waves,
// wave w owns queries [qbase+16w, +16). Uniform 128-key window [qbase-64, qbase+64).
// S^T = mfma(K, Q)  -> lane-local softmax (C-layout: col=q=l15, row=key=l4*4+j).
// PV: O^T = mfma(V^T, P^T); V^T in LDS (XOR-swizzled), P via LDS [16][72] per wave.
// Output written as GEMM2-A swizzled hi/lo planes.
// ============================================================================
__global__ __launch_bounds__(256) void attn_mfma(
    const unsigned* __restrict__ QKV, u16* __restrict__ OAh, u16* __restrict__ OAl)
{
    const int h  = blockIdx.x >> 6;
    const int qt = blockIdx.x & 63;
    const int qbase = qt << 6;
    const int kwin = qbase - 64;

    __shared__ u16 VTh[64 * 128], VTl[64 * 128];     // V^T, swizzled: [d][key^((d&15)<<3)]
    __shared__ u16 Ph_s[4][16 * 72], Pl_s[4][16 * 72]; // per-wave P half-buffer [q][64keys]

    const unsigned* Qg = QKV + ((size_t)(0 * NHEADS + h) * SLEN) * HEADD;
    const unsigned* Kg = QKV + ((size_t)(1 * NHEADS + h) * SLEN) * HEADD;
    const unsigned* Vg = QKV + ((size_t)(2 * NHEADS + h) * SLEN) * HEADD;

    const int tid = threadIdx.x;
    const int w = tid >> 6, lane = tid & 63;
    const int l15 = lane & 15, l4 = lane >> 4;

    // ---- stage V^T (unpack packed u32 -> hi/lo, swizzled scatter)
#pragma unroll
    for (int i = 0; i < 4; ++i) {
        int idx = i * 256 + tid;
        int key = idx >> 3;            // [0,128)
        int d8  = (idx & 7) * 8;
        int kg = kwin + key; if (kg < 0) kg = 0;   // clamped rows get P=0
        const unsigned* vp = Vg + (size_t)kg * 64 + d8;
        uint4 p0 = *(const uint4*)vp, p1 = *(const uint4*)(vp + 4);
        unsigned vv[8] = {p0.x, p0.y, p0.z, p0.w, p1.x, p1.y, p1.z, p1.w};
#pragma unroll
        for (int j = 0; j < 8; ++j) {
            int d = d8 + j;
            int kk = key ^ ((d & 15) << 3);
            VTh[d * 128 + kk] = (u16)(vv[j] & 0xffff);
            VTl[d * 128 + kk] = (u16)(vv[j] >> 16);
        }
    }
    __syncthreads();

    // ---- Q fragments (B-operand), direct from global packed u32
    const int qrow = qbase + w * 16 + l15;
    bf16x8 qh[2], ql[2];
#pragma unroll
    for (int ks = 0; ks < 2; ++ks) {
        const unsigned* qp = Qg + (size_t)qrow * 64 + ks * 32 + l4 * 8;
        uint4 a = *(const uint4*)qp, b = *(const uint4*)(qp + 4);
        union { unsigned u[4]; bf16x8 v; } H, L;
        H.u[0] = __builtin_amdgcn_perm(a.y, a.x, 0x05040100);
        H.u[1] = __builtin_amdgcn_perm(a.w, a.z, 0x05040100);
        H.u[2] = __builtin_amdgcn_perm(b.y, b.x, 0x05040100);
        H.u[3] = __builtin_amdgcn_perm(b.w, b.z, 0x05040100);
        L.u[0] = __builtin_amdgcn_perm(a.y, a.x, 0x07060302);
        L.u[1] = __builtin_amdgcn_perm(a.w, a.z, 0x07060302);
        L.u[2] = __builtin_amdgcn_perm(b.y, b.x, 0x07060302);
        L.u[3] = __builtin_amdgcn_perm(b.w, b.z, 0x07060302);
        qh[ks] = H.v; ql[ks] = L.v;
    }

    // ---- scores S^T over 8 key-tiles
    f32x4 st[8];
#pragma unroll
    for (int t = 0; t < 8; ++t) st[t] = f32x4{0.f, 0.f, 0.f, 0.f};
#pragma unroll
    for (int t = 0; t < 8; ++t) {
        int krow = kwin + 16 * t + l15; if (krow < 0) krow = 0;
#pragma unroll
        for (int ks = 0; ks < 2; ++ks) {
            const unsigned* kp = Kg + (size_t)krow * 64 + ks * 32 + l4 * 8;
            uint4 a = *(const uint4*)kp, b = *(const uint4*)(kp + 4);
            union { unsigned u[4]; bf16x8 v; } H, L;
            H.u[0] = __builtin_amdgcn_perm(a.y, a.x, 0x05040100);
            H.u[1] = __builtin_amdgcn_perm(a.w, a.z, 0x05040100);
            H.u[2] = __builtin_amdgcn_perm(b.y, b.x, 0x05040100);
            H.u[3] = __builtin_amdgcn_perm(b.w, b.z, 0x05040100);
            L.u[0] = __builtin_amdgcn_perm(a.y, a.x, 0x07060302);
            L.u[1] = __builtin_amdgcn_perm(a.w, a.z, 0x07060302);
            L.u[2] = __builtin_amdgcn_perm(b.y, b.x, 0x07060302);
            L.u[3] = __builtin_amdgcn_perm(b.w, b.z, 0x07060302);
            st[t] = MFMA(H.v, qh[ks], st[t]);
            st[t] = MFMA(H.v, ql[ks], st[t]);
            st[t] = MFMA(L.v, qh[ks], st[t]);
        }
    }

    // ---- analytic mask + softmax (lane-local + 2 shuffles)
    const int qg = qrow;
    float mx = -1e30f;
#pragma unroll
    for (int t = 0; t < 8; ++t)
#pragma unroll
        for (int j = 0; j < 4; ++j) {
            int kg = kwin + 16 * t + 4 * l4 + j;
            float s = st[t][j] * SCALE;
            bool ok = (kg >= 0) && (kg <= qg) && (qg - kg <= WIN);
            s = ok ? s : -1e30f;
            st[t][j] = s;
            mx = fmaxf(mx, s);
        }
    mx = fmaxf(mx, __shfl_xor(mx, 16));
    mx = fmaxf(mx, __shfl_xor(mx, 32));
    float lsum = 0.f;
#pragma unroll
    for (int t = 0; t < 8; ++t)
#pragma unroll
        for (int j = 0; j < 4; ++j) {
            float p = exp2f((st[t][j] - mx) * LOG2E);
            st[t][j] = p;
            lsum += p;
        }
    lsum += __shfl_xor(lsum, 16);
    lsum += __shfl_xor(lsum, 32);

    // ---- PV in two 64-key halves (P half-buffer reuse keeps LDS < 64KB)
    f32x4 o[4];
#pragma unroll
    for (int dt = 0; dt < 4; ++dt) o[dt] = f32x4{0.f, 0.f, 0.f, 0.f};

#pragma unroll
    for (int half = 0; half < 2; ++half) {
        // write P tiles (split-bf16), col = half-local key = tt*16 + 4*l4 + j
#pragma unroll
        for (int tt = 0; tt < 4; ++tt) {
            int t = half * 4 + tt;
            u16 phv[4], plv[4];
#pragma unroll
            for (int j = 0; j < 4; ++j) {
                float p = st[t][j];
                phv[j] = f2bf(p);
                plv[j] = f2bf(p - bf2f(phv[j]));
            }
            int pidx = l15 * 72 + tt * 16 + l4 * 4;
            *(uint2*)&Ph_s[w][pidx] = uint2{(unsigned)phv[0] | ((unsigned)phv[1] << 16),
                                            (unsigned)phv[2] | ((unsigned)phv[3] << 16)};
            *(uint2*)&Pl_s[w][pidx] = uint2{(unsigned)plv[0] | ((unsigned)plv[1] << 16),
                                            (unsigned)plv[2] | ((unsigned)plv[3] << 16)};
        }
        // same-wave RAW: compiler inserts lgkmcnt
#pragma unroll
        for (int kss = 0; kss < 2; ++kss) {
            int koff = kss * 32 + l4 * 8;
            bf16x8 pbh = *(const bf16x8*)&Ph_s[w][l15 * 72 + koff];
            bf16x8 pbl = *(const bf16x8*)&Pl_s[w][l15 * 72 + koff];
            int K0 = half * 64 + kss * 32 + l4 * 8;   // window-local key base
            int kk = K0 ^ (l15 << 3);                 // (d&15)==l15 for d=dt*16+l15
#pragma unroll
            for (int dt = 0; dt < 4; ++dt) {
                int d = dt * 16 + l15;
                bf16x8 vh = *(const bf16x8*)&VTh[d * 128 + kk];
                bf16x8 vl = *(const bf16x8*)&VTl[d * 128 + kk];
                o[dt] = MFMA(vh, pbh, o[dt]);
                o[dt] = MFMA(vh, pbl, o[dt]);
                o[dt] = MFMA(vl, pbh, o[dt]);
            }
        }
    }

    // ---- epilogue: O^T/lsum -> GEMM2-A swizzled hi/lo planes
    float inv = 1.0f / lsum;
    const int srow = qrow;
#pragma unroll
    for (int dt = 0; dt < 4; ++dt) {
        u16 hv[4], lv[4];
#pragma unroll
        for (int j = 0; j < 4; ++j) {
            float v = o[dt][j] * inv;
            hv[j] = f2bf(v);
            lv[j] = f2bf(v - bf2f(hv[j]));
        }
        int col0 = h * 64 + dt * 16 + l4 * 4;
        size_t di = (size_t)srow * 768 + (col0 >> 5) * 32
                  + (size_t)((((col0 >> 3) & 3) ^ (srow & 3))) * 8 + (col0 & 7);
        *(uint2*)(OAh + di) = uint2{(unsigned)hv[0] | ((unsigned)hv[1] << 16),
                                    (unsigned)hv[2] | ((unsigned)hv[3] << 16)};
        *(uint2*)(OAl + di) = uint2{(unsigned)lv[0] | ((unsigned)lv[1] << 16),
                                    (unsigned)lv[2] | ((unsigned)lv[3] << 16)};
    }
}

extern "C" void kernel_launch(void* const* d_in, const int* in_sizes, int n_in,
                              void* d_out, int out_size, void* d_ws, size_t ws_size,
                              hipStream_t stream)
{
    const float* hs   = (const float*)d_in[0];
    const float* wqkv = (const float*)d_in[1];
    const float* wo   = (const float*)d_in[2];
    const float* cosT = (const float*)d_in[3];
    const float* sinT = (const float*)d_in[4];
    // d_in[5] attention_mask: unused (mask applied analytically)
    float* out = (float*)d_out;

    char* p = (char*)d_ws;
    unsigned* qkvP = (unsigned*)p;      p += (size_t)3 * NHEADS * SLEN * HEADD * 4;  // 37.75 MB
    u16* hsH = (u16*)p;                 p += (size_t)SLEN * HDIM * 2;                // 6.29 MB
    u16* hsL = (u16*)p;                 p += (size_t)SLEN * HDIM * 2;
    u16* wqH = (u16*)p;                 p += (size_t)NQKV * HDIM * 2;                // 3.54 MB
    u16* wqL = (u16*)p;                 p += (size_t)NQKV * HDIM * 2;
    u16* woH = (u16*)p;                 p += (size_t)HDIM * HDIM * 2;                // 1.18 MB
    u16* woL = (u16*)p;                 p += (size_t)HDIM * HDIM * 2;
    // attention output planes alias the hs planes (hs only read by GEMM1, done by then)
    u16* oAh = hsH;
    u16* oAl = hsL;

    split_planes<<<2688, 256, 0, stream>>>(hs, wqkv, wo, hsH, hsL, wqH, wqL, woH, woL);

    dim3 g1(NQKV / 128, SLEN / 128);
    gemm_sp<1><<<g1, 256, 0, stream>>>(hsH, hsL, wqH, wqL, qkvP, SLEN, NQKV, HDIM, cosT, sinT);

    attn_mfma<<<NHEADS * (SLEN / 64), 256, 0, stream>>>(qkvP, oAh, oAl);

    dim3 g2(HDIM / 128, SLEN / 128);
    gemm_sp<0><<<g2, 256, 0, stream>>>(oAh, oAl, woH, woL, out, SLEN, HDIM, HDIM, nullptr, nullptr);
}

// Round 9
// 232.978 us; speedup vs baseline: 2.3752x; 1.0684x over previous
//
#include <hip/hip_runtime.h>

#define SLEN   4096
#define HDIM   768
#define NHEADS 12
#define HEADD  64
#define NQKV   2304
#define WIN    64

constexpr float SCALE = 0.125f;  // 64^-0.5
constexpr float LOG2E = 1.4426950408889634f;

typedef short bf16x8 __attribute__((ext_vector_type(8)));
typedef float f32x4  __attribute__((ext_vector_type(4)));
typedef unsigned short u16;

#define MFMA(a, b, c) __builtin_amdgcn_mfma_f32_16x16x32_bf16((a), (b), (c), 0, 0, 0)

#define GLDS(gp, lp) __builtin_amdgcn_global_load_lds( \
    (const __attribute__((address_space(1))) unsigned*)(gp), \
    (__attribute__((address_space(3))) unsigned*)(lp), 16, 0, 0)

// ---- bf16 split helpers: x ~= hi + lo, each bf16 (RN). Packed u32 = hi | lo<<16.
__device__ inline u16 f2bf(float x) {
    unsigned u = __float_as_uint(x);
    u += 0x7fff + ((u >> 16) & 1);
    return (u16)(u >> 16);
}
__device__ inline float bf2f(u16 b) { return __uint_as_float(((unsigned)b) << 16); }
__device__ inline unsigned packsplit(float x) {
    u16 h = f2bf(x);
    u16 l = f2bf(x - bf2f(h));
    return (unsigned)h | ((unsigned)l << 16);
}

// ============================================================================
// Pre-pass: split f32 [R][768] into hi/lo bf16 planes with quad-swizzle baked in.
// Plane layout (u16 units): elem (r,k) at r*768 + (k>>5)*32 + (((k>>3)&3)^(r&3))*8 + (k&7)
// ============================================================================
__global__ __launch_bounds__(256) void split_planes(
    const float* __restrict__ hs, const float* __restrict__ wq, const float* __restrict__ wo,
    u16* __restrict__ hsH, u16* __restrict__ hsL,
    u16* __restrict__ wqH, u16* __restrict__ wqL,
    u16* __restrict__ woH, u16* __restrict__ woL)
{
    int qid = blockIdx.x * 256 + threadIdx.x;   // one 8-elem quad per thread
    const float* src; u16 *dH, *dL; int r, k8;
    if (qid < 393216)      { src = hs; dH = hsH; dL = hsL; r = qid / 96; k8 = qid % 96; }
    else if (qid < 614400) { int q = qid - 393216; src = wq; dH = wqH; dL = wqL; r = q / 96; k8 = q % 96; }
    else                   { int q = qid - 614400; src = wo; dH = woH; dL = woL; r = q / 96; k8 = q % 96; }

    const float* p = src + (size_t)r * 768 + k8 * 8;
    float4 f0 = *(const float4*)p, f1 = *(const float4*)(p + 4);
    float fv[8] = {f0.x, f0.y, f0.z, f0.w, f1.x, f1.y, f1.z, f1.w};
    unsigned hh[4], ll[4];
#pragma unroll
    for (int i = 0; i < 4; ++i) {
        u16 h0 = f2bf(fv[2*i]),   h1 = f2bf(fv[2*i+1]);
        u16 l0 = f2bf(fv[2*i] - bf2f(h0)), l1 = f2bf(fv[2*i+1] - bf2f(h1));
        hh[i] = (unsigned)h0 | ((unsigned)h1 << 16);
        ll[i] = (unsigned)l0 | ((unsigned)l1 << 16);
    }
    size_t di = (size_t)r * 768 + (k8 >> 2) * 32 + (size_t)(((k8 & 3) ^ (r & 3))) * 8;
    *(uint4*)(dH + di) = uint4{hh[0], hh[1], hh[2], hh[3]};
    *(uint4*)(dL + di) = uint4{ll[0], ll[1], ll[2], ll[3]};
}

// ============================================================================
// GEMM: C = A(MxK) * B(NxK)^T, swizzled hi/lo planes, split-bf16 (3 MFMA).
// BM x 128 tile, BK=32, 256 thr = 4 waves (2x2). Double-buffered LDS with
// prefetch-before-compute (one barrier per K-step; stage latency hides under
// MFMA). 1D grid + XCD swizzle (grid % 8 == 0 guaranteed by caller).
// MODE 0: fp32 row-major C. MODE 1: QKV epilogue (RoPE, packed-u32 scatter).
// ============================================================================
template <int BM, int MODE>
__global__ __launch_bounds__(256) void gemm_sp(
    const u16* __restrict__ Ah, const u16* __restrict__ Al,
    const u16* __restrict__ Bh, const u16* __restrict__ Bl,
    void* __restrict__ Cv, int N, int K,
    const float* __restrict__ cosT, const float* __restrict__ sinT, int NBX)
{
    constexpr int ASZ = BM * 32;   // u16 per A plane buffer
    constexpr int MF  = BM / 32;   // m-frags per wave (wave rows = MF*16)
    __shared__ u16 sAh[2][ASZ], sAl[2][ASZ], sBh[2][4096], sBl[2][4096];

    const int tid = threadIdx.x;
    const int w = tid >> 6, lane = tid & 63;
    const int wr = w >> 1, wc = w & 1;
    const int l15 = lane & 15, l4 = lane >> 4;
    const int quad = lane & 3, rl = lane >> 2;

    // XCD-aware block swizzle: 8 contiguous chunks
    const int cpx = gridDim.x >> 3;
    const int bsw = (blockIdx.x & 7) * cpx + (blockIdx.x >> 3);
    const int bx = bsw % NBX, by = bsw / NBX;
    const int rowBase = by * BM, colBase = bx * 128;

    const size_t strB = (size_t)K * 2;  // plane row stride in bytes
    const char* Ahb = (const char*)Ah; const char* Alb = (const char*)Al;
    const char* Bhb = (const char*)Bh; const char* Blb = (const char*)Bl;

    f32x4 acc[MF][4];
#pragma unroll
    for (int m = 0; m < MF; ++m)
#pragma unroll
        for (int n = 0; n < 4; ++n) acc[m][n] = f32x4{0.f, 0.f, 0.f, 0.f};

    auto stage = [&](int bi, int kt) {
        size_t kb = (size_t)kt * 64 + quad * 16;
#pragma unroll
        for (int i = 0; i < BM / 64; ++i) {
            int row = i * 64 + w * 16 + rl;
            size_t go = (size_t)(rowBase + row) * strB + kb;
            unsigned lo = i * 4096 + w * 1024;
            GLDS(Ahb + go, (char*)(&sAh[bi][0]) + lo);
            GLDS(Alb + go, (char*)(&sAl[bi][0]) + lo);
        }
#pragma unroll
        for (int i = 0; i < 2; ++i) {
            int row = i * 64 + w * 16 + rl;
            size_t go = (size_t)(colBase + row) * strB + kb;
            unsigned lo = i * 4096 + w * 1024;
            GLDS(Bhb + go, (char*)(&sBh[bi][0]) + lo);
            GLDS(Blb + go, (char*)(&sBl[bi][0]) + lo);
        }
    };

    const int nkt = K >> 5;
    stage(0, 0);
    int cur = 0;
    for (int kt = 0; kt < nkt; ++kt) {
        __syncthreads();                       // stage(kt) done; prior reads drained
        if (kt + 1 < nkt) stage(cur ^ 1, kt + 1);   // prefetch hides under compute

        bf16x8 ah[MF], al[MF];
#pragma unroll
        for (int m = 0; m < MF; ++m) {
            int row = wr * (MF * 16) + m * 16 + l15;
            int byt = row * 64 + ((l4 * 16) ^ ((row & 3) << 4));
            ah[m] = *(const bf16x8*)((const char*)(&sAh[cur][0]) + byt);
            al[m] = *(const bf16x8*)((const char*)(&sAl[cur][0]) + byt);
        }
#pragma unroll
        for (int n = 0; n < 4; ++n) {
            int row = wc * 64 + n * 16 + l15;
            int byt = row * 64 + ((l4 * 16) ^ ((row & 3) << 4));
            bf16x8 bh = *(const bf16x8*)((const char*)(&sBh[cur][0]) + byt);
            bf16x8 bl = *(const bf16x8*)((const char*)(&sBl[cur][0]) + byt);
#pragma unroll
            for (int m = 0; m < MF; ++m) {
                acc[m][n] = MFMA(ah[m], bh, acc[m][n]);
                acc[m][n] = MFMA(ah[m], bl, acc[m][n]);
                acc[m][n] = MFMA(al[m], bh, acc[m][n]);
            }
        }
        cur ^= 1;
    }

    // C/D layout: col = lane&15, row = (lane>>4)*4 + reg  [HW-validated]
    if constexpr (MODE == 0) {
        float* C = (float*)Cv;
#pragma unroll
        for (int m = 0; m < MF; ++m)
#pragma unroll
            for (int n = 0; n < 4; ++n)
#pragma unroll
                for (int j = 0; j < 4; ++j) {
                    int row = rowBase + wr * (MF * 16) + m * 16 + l4 * 4 + j;
                    int col = colBase + wc * 64 + n * 16 + l15;
                    C[(size_t)row * N + col] = acc[m][n][j];
                }
    } else {
        // wave's 64-col span = one (tensor, head); RoPE pairs (n, n+2)
        unsigned* QKVp = (unsigned*)Cv;
        const int span = colBase + wc * 64;
        const int t = span / HDIM;
        const int hh = (span - t * HDIM) >> 6;
        unsigned* dstH = QKVp + (((size_t)t * NHEADS + hh) * SLEN) * HEADD;
#pragma unroll
        for (int m = 0; m < MF; ++m)
#pragma unroll
            for (int np = 0; np < 2; ++np)
#pragma unroll
                for (int j = 0; j < 4; ++j) {
                    int srow = rowBase + wr * (MF * 16) + m * 16 + l4 * 4 + j;
                    int dlo = np * 16 + l15;  // < 32
                    float lo = acc[m][np][j];
                    float hi = acc[m][np + 2][j];
                    unsigned* dst = dstH + (size_t)srow * HEADD;
                    if (t < 2) {
                        float c = cosT[srow * HEADD + dlo];
                        float s = sinT[srow * HEADD + dlo];
                        float nlo = lo * c - hi * s;
                        float nhi = hi * c + lo * s;
                        dst[dlo]      = packsplit(nlo);
                        dst[dlo + 32] = packsplit(nhi);
                    } else {
                        dst[dlo]      = packsplit(lo);
                        dst[dlo + 32] = packsplit(hi);
                    }
                }
    }
}

// ============================================================================
// MFMA sliding-window attention. Block = (head, 64-query tile), 256 thr = 4 waves.
// S^T = mfma(K, Q) -> lane-local softmax; PV: O^T = mfma(V^T, P^T).
// Output written as GEMM2-A swizzled hi/lo planes.
// ============================================================================
__global__ __launch_bounds__(256) void attn_mfma(
    const unsigned* __restrict__ QKV, u16* __restrict__ OAh, u16* __restrict__ OAl)
{
    const int h  = blockIdx.x >> 6;
    const int qt = blockIdx.x & 63;
    const int qbase = qt << 6;
    const int kwin = qbase - 64;

    __shared__ u16 VTh[64 * 128], VTl[64 * 128];     // V^T, swizzled: [d][key^((d&15)<<3)]
    __shared__ u16 Ph_s[4][16 * 72], Pl_s[4][16 * 72]; // per-wave P half-buffer [q][64keys]

    const unsigned* Qg = QKV + ((size_t)(0 * NHEADS + h) * SLEN) * HEADD;
    const unsigned* Kg = QKV + ((size_t)(1 * NHEADS + h) * SLEN) * HEADD;
    const unsigned* Vg = QKV + ((size_t)(2 * NHEADS + h) * SLEN) * HEADD;

    const int tid = threadIdx.x;
    const int w = tid >> 6, lane = tid & 63;
    const int l15 = lane & 15, l4 = lane >> 4;

    // ---- stage V^T (unpack packed u32 -> hi/lo, swizzled scatter)
#pragma unroll
    for (int i = 0; i < 4; ++i) {
        int idx = i * 256 + tid;
        int key = idx >> 3;            // [0,128)
        int d8  = (idx & 7) * 8;
        int kg = kwin + key; if (kg < 0) kg = 0;   // clamped rows get P=0
        const unsigned* vp = Vg + (size_t)kg * 64 + d8;
        uint4 p0 = *(const uint4*)vp, p1 = *(const uint4*)(vp + 4);
        unsigned vv[8] = {p0.x, p0.y, p0.z, p0.w, p1.x, p1.y, p1.z, p1.w};
#pragma unroll
        for (int j = 0; j < 8; ++j) {
            int d = d8 + j;
            int kk = key ^ ((d & 15) << 3);
            VTh[d * 128 + kk] = (u16)(vv[j] & 0xffff);
            VTl[d * 128 + kk] = (u16)(vv[j] >> 16);
        }
    }
    __syncthreads();

    // ---- Q fragments (B-operand), direct from global packed u32
    const int qrow = qbase + w * 16 + l15;
    bf16x8 qh[2], ql[2];
#pragma unroll
    for (int ks = 0; ks < 2; ++ks) {
        const unsigned* qp = Qg + (size_t)qrow * 64 + ks * 32 + l4 * 8;
        uint4 a = *(const uint4*)qp, b = *(const uint4*)(qp + 4);
        union { unsigned u[4]; bf16x8 v; } H, L;
        H.u[0] = __builtin_amdgcn_perm(a.y, a.x, 0x05040100);
        H.u[1] = __builtin_amdgcn_perm(a.w, a.z, 0x05040100);
        H.u[2] = __builtin_amdgcn_perm(b.y, b.x, 0x05040100);
        H.u[3] = __builtin_amdgcn_perm(b.w, b.z, 0x05040100);
        L.u[0] = __builtin_amdgcn_perm(a.y, a.x, 0x07060302);
        L.u[1] = __builtin_amdgcn_perm(a.w, a.z, 0x07060302);
        L.u[2] = __builtin_amdgcn_perm(b.y, b.x, 0x07060302);
        L.u[3] = __builtin_amdgcn_perm(b.w, b.z, 0x07060302);
        qh[ks] = H.v; ql[ks] = L.v;
    }

    // ---- scores S^T over 8 key-tiles
    f32x4 st[8];
#pragma unroll
    for (int t = 0; t < 8; ++t) st[t] = f32x4{0.f, 0.f, 0.f, 0.f};
#pragma unroll
    for (int t = 0; t < 8; ++t) {
        int krow = kwin + 16 * t + l15; if (krow < 0) krow = 0;
#pragma unroll
        for (int ks = 0; ks < 2; ++ks) {
            const unsigned* kp = Kg + (size_t)krow * 64 + ks * 32 + l4 * 8;
            uint4 a = *(const uint4*)kp, b = *(const uint4*)(kp + 4);
            union { unsigned u[4]; bf16x8 v; } H, L;
            H.u[0] = __builtin_amdgcn_perm(a.y, a.x, 0x05040100);
            H.u[1] = __builtin_amdgcn_perm(a.w, a.z, 0x05040100);
            H.u[2] = __builtin_amdgcn_perm(b.y, b.x, 0x05040100);
            H.u[3] = __builtin_amdgcn_perm(b.w, b.z, 0x05040100);
            L.u[0] = __builtin_amdgcn_perm(a.y, a.x, 0x07060302);
            L.u[1] = __builtin_amdgcn_perm(a.w, a.z, 0x07060302);
            L.u[2] = __builtin_amdgcn_perm(b.y, b.x, 0x07060302);
            L.u[3] = __builtin_amdgcn_perm(b.w, b.z, 0x07060302);
            st[t] = MFMA(H.v, qh[ks], st[t]);
            st[t] = MFMA(H.v, ql[ks], st[t]);
            st[t] = MFMA(L.v, qh[ks], st[t]);
        }
    }

    // ---- analytic mask + softmax (lane-local + 2 shuffles)
    const int qg = qrow;
    float mx = -1e30f;
#pragma unroll
    for (int t = 0; t < 8; ++t)
#pragma unroll
        for (int j = 0; j < 4; ++j) {
            int kg = kwin + 16 * t + 4 * l4 + j;
            float s = st[t][j] * SCALE;
            bool ok = (kg >= 0) && (kg <= qg) && (qg - kg <= WIN);
            s = ok ? s : -1e30f;
            st[t][j] = s;
            mx = fmaxf(mx, s);
        }
    mx = fmaxf(mx, __shfl_xor(mx, 16));
    mx = fmaxf(mx, __shfl_xor(mx, 32));
    float lsum = 0.f;
#pragma unroll
    for (int t = 0; t < 8; ++t)
#pragma unroll
        for (int j = 0; j < 4; ++j) {
            float p = exp2f((st[t][j] - mx) * LOG2E);
            st[t][j] = p;
            lsum += p;
        }
    lsum += __shfl_xor(lsum, 16);
    lsum += __shfl_xor(lsum, 32);

    // ---- PV in two 64-key halves
    f32x4 o[4];
#pragma unroll
    for (int dt = 0; dt < 4; ++dt) o[dt] = f32x4{0.f, 0.f, 0.f, 0.f};

#pragma unroll
    for (int half = 0; half < 2; ++half) {
#pragma unroll
        for (int tt = 0; tt < 4; ++tt) {
            int t = half * 4 + tt;
            u16 phv[4], plv[4];
#pragma unroll
            for (int j = 0; j < 4; ++j) {
                float p = st[t][j];
                phv[j] = f2bf(p);
                plv[j] = f2bf(p - bf2f(phv[j]));
            }
            int pidx = l15 * 72 + tt * 16 + l4 * 4;
            *(uint2*)&Ph_s[w][pidx] = uint2{(unsigned)phv[0] | ((unsigned)phv[1] << 16),
                                            (unsigned)phv[2] | ((unsigned)phv[3] << 16)};
            *(uint2*)&Pl_s[w][pidx] = uint2{(unsigned)plv[0] | ((unsigned)plv[1] << 16),
                                            (unsigned)plv[2] | ((unsigned)plv[3] << 16)};
        }
#pragma unroll
        for (int kss = 0; kss < 2; ++kss) {
            int koff = kss * 32 + l4 * 8;
            bf16x8 pbh = *(const bf16x8*)&Ph_s[w][l15 * 72 + koff];
            bf16x8 pbl = *(const bf16x8*)&Pl_s[w][l15 * 72 + koff];
            int K0 = half * 64 + kss * 32 + l4 * 8;   // window-local key base
            int kk = K0 ^ (l15 << 3);                 // (d&15)==l15 for d=dt*16+l15
#pragma unroll
            for (int dt = 0; dt < 4; ++dt) {
                int d = dt * 16 + l15;
                bf16x8 vh = *(const bf16x8*)&VTh[d * 128 + kk];
                bf16x8 vl = *(const bf16x8*)&VTl[d * 128 + kk];
                o[dt] = MFMA(vh, pbh, o[dt]);
                o[dt] = MFMA(vh, pbl, o[dt]);
                o[dt] = MFMA(vl, pbh, o[dt]);
            }
        }
    }

    // ---- epilogue: O^T/lsum -> GEMM2-A swizzled hi/lo planes
    float inv = 1.0f / lsum;
    const int srow = qrow;
#pragma unroll
    for (int dt = 0; dt < 4; ++dt) {
        u16 hv[4], lv[4];
#pragma unroll
        for (int j = 0; j < 4; ++j) {
            float v = o[dt][j] * inv;
            hv[j] = f2bf(v);
            lv[j] = f2bf(v - bf2f(hv[j]));
        }
        int col0 = h * 64 + dt * 16 + l4 * 4;
        size_t di = (size_t)srow * 768 + (col0 >> 5) * 32
                  + (size_t)((((col0 >> 3) & 3) ^ (srow & 3))) * 8 + (col0 & 7);
        *(uint2*)(OAh + di) = uint2{(unsigned)hv[0] | ((unsigned)hv[1] << 16),
                                    (unsigned)hv[2] | ((unsigned)hv[3] << 16)};
        *(uint2*)(OAl + di) = uint2{(unsigned)lv[0] | ((unsigned)lv[1] << 16),
                                    (unsigned)lv[2] | ((unsigned)lv[3] << 16)};
    }
}

extern "C" void kernel_launch(void* const* d_in, const int* in_sizes, int n_in,
                              void* d_out, int out_size, void* d_ws, size_t ws_size,
                              hipStream_t stream)
{
    const float* hs   = (const float*)d_in[0];
    const float* wqkv = (const float*)d_in[1];
    const float* wo   = (const float*)d_in[2];
    const float* cosT = (const float*)d_in[3];
    const float* sinT = (const float*)d_in[4];
    // d_in[5] attention_mask: unused (mask applied analytically)
    float* out = (float*)d_out;

    char* p = (char*)d_ws;
    unsigned* qkvP = (unsigned*)p;      p += (size_t)3 * NHEADS * SLEN * HEADD * 4;  // 37.75 MB
    u16* hsH = (u16*)p;                 p += (size_t)SLEN * HDIM * 2;                // 6.29 MB
    u16* hsL = (u16*)p;                 p += (size_t)SLEN * HDIM * 2;
    u16* wqH = (u16*)p;                 p += (size_t)NQKV * HDIM * 2;                // 3.54 MB
    u16* wqL = (u16*)p;                 p += (size_t)NQKV * HDIM * 2;
    u16* woH = (u16*)p;                 p += (size_t)HDIM * HDIM * 2;                // 1.18 MB
    u16* woL = (u16*)p;                 p += (size_t)HDIM * HDIM * 2;
    // attention output planes alias the hs planes (hs only read by GEMM1, done by then)
    u16* oAh = hsH;
    u16* oAl = hsL;

    split_planes<<<2688, 256, 0, stream>>>(hs, wqkv, wo, hsH, hsL, wqH, wqL, woH, woL);

    // GEMM1: 128x128 tiles, 1D grid 576 = 18 cols x 32 rows (576 % 8 == 0)
    gemm_sp<128, 1><<<576, 256, 0, stream>>>(hsH, hsL, wqH, wqL, qkvP,
                                             NQKV, HDIM, cosT, sinT, 18);

    attn_mfma<<<NHEADS * (SLEN / 64), 256, 0, stream>>>(qkvP, oAh, oAl);

    // GEMM2: 64x128 tiles, 1D grid 384 = 6 cols x 64 rows (384 % 8 == 0)
    gemm_sp<64, 0><<<384, 256, 0, stream>>>(oAh, oAl, woH, woL, out,
                                            HDIM, HDIM, nullptr, nullptr, 6);
}

// Round 11
// 212.249 us; speedup vs baseline: 2.6072x; 1.0977x over previous
//
#include <hip/hip_runtime.h>

#define SLEN   4096
#define HDIM   768
#define NHEADS 12
#define HEADD  64
#define NQKV   2304
#define WIN    64

constexpr float SCALE = 0.125f;  // 64^-0.5
constexpr float LOG2E = 1.4426950408889634f;

typedef _Float16 f16x8 __attribute__((ext_vector_type(8)));
typedef float f32x4  __attribute__((ext_vector_type(4)));
typedef unsigned short u16;

#define MFMA(a, b, c) __builtin_amdgcn_mfma_f32_16x16x32_f16((a), (b), (c), 0, 0, 0)

#define GLDS(gp, lp) __builtin_amdgcn_global_load_lds( \
    (const __attribute__((address_space(1))) unsigned*)(gp), \
    (__attribute__((address_space(3))) unsigned*)(lp), 16, 0, 0)

// ---- fp16 split helpers: x ~= h + l, each fp16 (RN, ~22 mantissa bits total).
// Packed u32 = h | l<<16.
__device__ inline u16 f2h(float x) {
    union { _Float16 f; u16 u; } c; c.f = (_Float16)x; return c.u;
}
__device__ inline float h2f(u16 b) {
    union { _Float16 f; u16 u; } c; c.u = b; return (float)c.f;
}
__device__ inline unsigned packsplit(float x) {
    u16 h = f2h(x);
    u16 l = f2h(x - h2f(h));
    return (unsigned)h | ((unsigned)l << 16);
}

// ============================================================================
// Pre-pass: split f32 [R][768] into hi/lo fp16 planes with quad-swizzle baked in.
// Plane layout (u16 units): elem (r,k) at r*768 + (k>>5)*32 + (((k>>3)&3)^(r&3))*8 + (k&7)
// hs: hi plane only (GEMM 2-term drops the A-lo residual).
// ============================================================================
__global__ __launch_bounds__(256) void split_planes(
    const float* __restrict__ hs, const float* __restrict__ wq, const float* __restrict__ wo,
    u16* __restrict__ hsH,
    u16* __restrict__ wqH, u16* __restrict__ wqL,
    u16* __restrict__ woH, u16* __restrict__ woL)
{
    int qid = blockIdx.x * 256 + threadIdx.x;   // one 8-elem quad per thread
    const float* src; u16 *dH, *dL; int r, k8;
    if (qid < 393216)      { src = hs; dH = hsH; dL = nullptr; r = qid / 96; k8 = qid % 96; }
    else if (qid < 614400) { int q = qid - 393216; src = wq; dH = wqH; dL = wqL; r = q / 96; k8 = q % 96; }
    else                   { int q = qid - 614400; src = wo; dH = woH; dL = woL; r = q / 96; k8 = q % 96; }

    const float* p = src + (size_t)r * 768 + k8 * 8;
    float4 f0 = *(const float4*)p, f1 = *(const float4*)(p + 4);
    float fv[8] = {f0.x, f0.y, f0.z, f0.w, f1.x, f1.y, f1.z, f1.w};
    unsigned hh[4], ll[4];
#pragma unroll
    for (int i = 0; i < 4; ++i) {
        u16 h0 = f2h(fv[2*i]),              h1 = f2h(fv[2*i+1]);
        u16 l0 = f2h(fv[2*i] - h2f(h0)),    l1 = f2h(fv[2*i+1] - h2f(h1));
        hh[i] = (unsigned)h0 | ((unsigned)h1 << 16);
        ll[i] = (unsigned)l0 | ((unsigned)l1 << 16);
    }
    size_t di = (size_t)r * 768 + (k8 >> 2) * 32 + (size_t)(((k8 & 3) ^ (r & 3))) * 8;
    *(uint4*)(dH + di) = uint4{hh[0], hh[1], hh[2], hh[3]};
    if (dL) *(uint4*)(dL + di) = uint4{ll[0], ll[1], ll[2], ll[3]};
}

// ============================================================================
// GEMM: C = A(MxK) * B(NxK)^T, fp16 2-term split: C ~= Ah*Bh + Ah*Bl
// (dropped Al*Bh ~ 2^-11 rel). BM x 128 tile, BK=32, 256 thr = 4 waves (2x2).
// Double-buffered LDS, prefetch-before-compute, XCD-swizzled 1D grid.
// MODE 0: fp32 row-major C. MODE 1: QKV epilogue (RoPE, packed-u32 scatter).
// ============================================================================
template <int BM, int MODE>
__global__ __launch_bounds__(256) void gemm_sp(
    const u16* __restrict__ Ah,
    const u16* __restrict__ Bh, const u16* __restrict__ Bl,
    void* __restrict__ Cv, int N, int K,
    const float* __restrict__ cosT, const float* __restrict__ sinT, int NBX)
{
    constexpr int ASZ = BM * 32;   // u16 per A plane buffer
    constexpr int MF  = BM / 32;   // m-frags per wave (wave rows = MF*16)
    __shared__ u16 sAh[2][ASZ], sBh[2][4096], sBl[2][4096];

    const int tid = threadIdx.x;
    const int w = tid >> 6, lane = tid & 63;
    const int wr = w >> 1, wc = w & 1;
    const int l15 = lane & 15, l4 = lane >> 4;
    const int quad = lane & 3, rl = lane >> 2;

    // XCD-aware block swizzle: 8 contiguous chunks
    const int cpx = gridDim.x >> 3;
    const int bsw = (blockIdx.x & 7) * cpx + (blockIdx.x >> 3);
    const int bx = bsw % NBX, by = bsw / NBX;
    const int rowBase = by * BM, colBase = bx * 128;

    const size_t strB = (size_t)K * 2;  // plane row stride in bytes
    const char* Ahb = (const char*)Ah;
    const char* Bhb = (const char*)Bh; const char* Blb = (const char*)Bl;

    f32x4 acc[MF][4];
#pragma unroll
    for (int m = 0; m < MF; ++m)
#pragma unroll
        for (int n = 0; n < 4; ++n) acc[m][n] = f32x4{0.f, 0.f, 0.f, 0.f};

    auto stage = [&](int bi, int kt) {
        size_t kb = (size_t)kt * 64 + quad * 16;
#pragma unroll
        for (int i = 0; i < BM / 64; ++i) {
            int row = i * 64 + w * 16 + rl;
            size_t go = (size_t)(rowBase + row) * strB + kb;
            unsigned lo = i * 4096 + w * 1024;
            GLDS(Ahb + go, (char*)(&sAh[bi][0]) + lo);
        }
#pragma unroll
        for (int i = 0; i < 2; ++i) {
            int row = i * 64 + w * 16 + rl;
            size_t go = (size_t)(colBase + row) * strB + kb;
            unsigned lo = i * 4096 + w * 1024;
            GLDS(Bhb + go, (char*)(&sBh[bi][0]) + lo);
            GLDS(Blb + go, (char*)(&sBl[bi][0]) + lo);
        }
    };

    const int nkt = K >> 5;
    stage(0, 0);
    int cur = 0;
    for (int kt = 0; kt < nkt; ++kt) {
        __syncthreads();                       // stage(kt) landed; prior reads drained
        if (kt + 1 < nkt) stage(cur ^ 1, kt + 1);   // prefetch hides under compute

        f16x8 ah[MF];
#pragma unroll
        for (int m = 0; m < MF; ++m) {
            int row = wr * (MF * 16) + m * 16 + l15;
            int byt = row * 64 + ((l4 * 16) ^ ((row & 3) << 4));
            ah[m] = *(const f16x8*)((const char*)(&sAh[cur][0]) + byt);
        }
#pragma unroll
        for (int n = 0; n < 4; ++n) {
            int row = wc * 64 + n * 16 + l15;
            int byt = row * 64 + ((l4 * 16) ^ ((row & 3) << 4));
            f16x8 bh = *(const f16x8*)((const char*)(&sBh[cur][0]) + byt);
            f16x8 bl = *(const f16x8*)((const char*)(&sBl[cur][0]) + byt);
#pragma unroll
            for (int m = 0; m < MF; ++m) {
                acc[m][n] = MFMA(ah[m], bh, acc[m][n]);
                acc[m][n] = MFMA(ah[m], bl, acc[m][n]);
            }
        }
        cur ^= 1;
    }

    // C/D layout: col = lane&15, row = (lane>>4)*4 + reg  [HW-validated]
    if constexpr (MODE == 0) {
        float* C = (float*)Cv;
#pragma unroll
        for (int m = 0; m < MF; ++m)
#pragma unroll
            for (int n = 0; n < 4; ++n)
#pragma unroll
                for (int j = 0; j < 4; ++j) {
                    int row = rowBase + wr * (MF * 16) + m * 16 + l4 * 4 + j;
                    int col = colBase + wc * 64 + n * 16 + l15;
                    C[(size_t)row * N + col] = acc[m][n][j];
                }
    } else {
        // wave's 64-col span = one (tensor, head); RoPE pairs (n, n+2)
        unsigned* QKVp = (unsigned*)Cv;
        const int span = colBase + wc * 64;
        const int t = span / HDIM;
        const int hh = (span - t * HDIM) >> 6;
        unsigned* dstH = QKVp + (((size_t)t * NHEADS + hh) * SLEN) * HEADD;
#pragma unroll
        for (int m = 0; m < MF; ++m)
#pragma unroll
            for (int np = 0; np < 2; ++np)
#pragma unroll
                for (int j = 0; j < 4; ++j) {
                    int srow = rowBase + wr * (MF * 16) + m * 16 + l4 * 4 + j;
                    int dlo = np * 16 + l15;  // < 32
                    float lo = acc[m][np][j];
                    float hi = acc[m][np + 2][j];
                    unsigned* dst = dstH + (size_t)srow * HEADD;
                    if (t < 2) {
                        float c = cosT[srow * HEADD + dlo];
                        float s = sinT[srow * HEADD + dlo];
                        float nlo = lo * c - hi * s;
                        float nhi = hi * c + lo * s;
                        dst[dlo]      = packsplit(nlo);
                        dst[dlo + 32] = packsplit(nhi);
                    } else {
                        dst[dlo]      = packsplit(lo);
                        dst[dlo + 32] = packsplit(hi);
                    }
                }
    }
}

// ============================================================================
// MFMA sliding-window attention (fp16, 3-term split — accuracy insurance).
// Block = (head, 64-query tile), 256 thr = 4 waves.
// S^T = mfma(K, Q) -> lane-local softmax; PV: O^T = mfma(V^T, P^T).
// Output written as GEMM2-A hi plane only (2-term GEMM2 needs no lo).
// ============================================================================
__global__ __launch_bounds__(256) void attn_mfma(
    const unsigned* __restrict__ QKV, u16* __restrict__ OAh)
{
    const int h  = blockIdx.x >> 6;
    const int qt = blockIdx.x & 63;
    const int qbase = qt << 6;
    const int kwin = qbase - 64;

    __shared__ u16 VTh[64 * 128], VTl[64 * 128];     // V^T, swizzled: [d][key^((d&15)<<3)]
    __shared__ u16 Ph_s[4][16 * 72], Pl_s[4][16 * 72]; // per-wave P half-buffer [q][64keys]

    const unsigned* Qg = QKV + ((size_t)(0 * NHEADS + h) * SLEN) * HEADD;
    const unsigned* Kg = QKV + ((size_t)(1 * NHEADS + h) * SLEN) * HEADD;
    const unsigned* Vg = QKV + ((size_t)(2 * NHEADS + h) * SLEN) * HEADD;

    const int tid = threadIdx.x;
    const int w = tid >> 6, lane = tid & 63;
    const int l15 = lane & 15, l4 = lane >> 4;

    // ---- stage V^T (unpack packed u32 -> hi/lo, swizzled scatter)
#pragma unroll
    for (int i = 0; i < 4; ++i) {
        int idx = i * 256 + tid;
        int key = idx >> 3;            // [0,128)
        int d8  = (idx & 7) * 8;
        int kg = kwin + key; if (kg < 0) kg = 0;   // clamped rows get P=0
        const unsigned* vp = Vg + (size_t)kg * 64 + d8;
        uint4 p0 = *(const uint4*)vp, p1 = *(const uint4*)(vp + 4);
        unsigned vv[8] = {p0.x, p0.y, p0.z, p0.w, p1.x, p1.y, p1.z, p1.w};
#pragma unroll
        for (int j = 0; j < 8; ++j) {
            int d = d8 + j;
            int kk = key ^ ((d & 15) << 3);
            VTh[d * 128 + kk] = (u16)(vv[j] & 0xffff);
            VTl[d * 128 + kk] = (u16)(vv[j] >> 16);
        }
    }
    __syncthreads();

    // ---- Q fragments (B-operand), direct from global packed u32
    const int qrow = qbase + w * 16 + l15;
    f16x8 qh[2], ql[2];
#pragma unroll
    for (int ks = 0; ks < 2; ++ks) {
        const unsigned* qp = Qg + (size_t)qrow * 64 + ks * 32 + l4 * 8;
        uint4 a = *(const uint4*)qp, b = *(const uint4*)(qp + 4);
        union { unsigned u[4]; f16x8 v; } H, L;
        H.u[0] = __builtin_amdgcn_perm(a.y, a.x, 0x05040100);
        H.u[1] = __builtin_amdgcn_perm(a.w, a.z, 0x05040100);
        H.u[2] = __builtin_amdgcn_perm(b.y, b.x, 0x05040100);
        H.u[3] = __builtin_amdgcn_perm(b.w, b.z, 0x05040100);
        L.u[0] = __builtin_amdgcn_perm(a.y, a.x, 0x07060302);
        L.u[1] = __builtin_amdgcn_perm(a.w, a.z, 0x07060302);
        L.u[2] = __builtin_amdgcn_perm(b.y, b.x, 0x07060302);
        L.u[3] = __builtin_amdgcn_perm(b.w, b.z, 0x07060302);
        qh[ks] = H.v; ql[ks] = L.v;
    }

    // ---- scores S^T over 8 key-tiles
    f32x4 st[8];
#pragma unroll
    for (int t = 0; t < 8; ++t) st[t] = f32x4{0.f, 0.f, 0.f, 0.f};
#pragma unroll
    for (int t = 0; t < 8; ++t) {
        int krow = kwin + 16 * t + l15; if (krow < 0) krow = 0;
#pragma unroll
        for (int ks = 0; ks < 2; ++ks) {
            const unsigned* kp = Kg + (size_t)krow * 64 + ks * 32 + l4 * 8;
            uint4 a = *(const uint4*)kp, b = *(const uint4*)(kp + 4);
            union { unsigned u[4]; f16x8 v; } H, L;
            H.u[0] = __builtin_amdgcn_perm(a.y, a.x, 0x05040100);
            H.u[1] = __builtin_amdgcn_perm(a.w, a.z, 0x05040100);
            H.u[2] = __builtin_amdgcn_perm(b.y, b.x, 0x05040100);
            H.u[3] = __builtin_amdgcn_perm(b.w, b.z, 0x05040100);
            L.u[0] = __builtin_amdgcn_perm(a.y, a.x, 0x07060302);
            L.u[1] = __builtin_amdgcn_perm(a.w, a.z, 0x07060302);
            L.u[2] = __builtin_amdgcn_perm(b.y, b.x, 0x07060302);
            L.u[3] = __builtin_amdgcn_perm(b.w, b.z, 0x07060302);
            st[t] = MFMA(H.v, qh[ks], st[t]);
            st[t] = MFMA(H.v, ql[ks], st[t]);
            st[t] = MFMA(L.v, qh[ks], st[t]);
        }
    }

    // ---- analytic mask + softmax (lane-local + 2 shuffles)
    const int qg = qrow;
    float mx = -1e30f;
#pragma unroll
    for (int t = 0; t < 8; ++t)
#pragma unroll
        for (int j = 0; j < 4; ++j) {
            int kg = kwin + 16 * t + 4 * l4 + j;
            float s = st[t][j] * SCALE;
            bool ok = (kg >= 0) && (kg <= qg) && (qg - kg <= WIN);
            s = ok ? s : -1e30f;
            st[t][j] = s;
            mx = fmaxf(mx, s);
        }
    mx = fmaxf(mx, __shfl_xor(mx, 16));
    mx = fmaxf(mx, __shfl_xor(mx, 32));
    float lsum = 0.f;
#pragma unroll
    for (int t = 0; t < 8; ++t)
#pragma unroll
        for (int j = 0; j < 4; ++j) {
            float p = exp2f((st[t][j] - mx) * LOG2E);
            st[t][j] = p;
            lsum += p;
        }
    lsum += __shfl_xor(lsum, 16);
    lsum += __shfl_xor(lsum, 32);

    // ---- PV in two 64-key halves
    f32x4 o[4];
#pragma unroll
    for (int dt = 0; dt < 4; ++dt) o[dt] = f32x4{0.f, 0.f, 0.f, 0.f};

#pragma unroll
    for (int half = 0; half < 2; ++half) {
#pragma unroll
        for (int tt = 0; tt < 4; ++tt) {
            int t = half * 4 + tt;
            u16 phv[4], plv[4];
#pragma unroll
            for (int j = 0; j < 4; ++j) {
                float p = st[t][j];
                phv[j] = f2h(p);
                plv[j] = f2h(p - h2f(phv[j]));
            }
            int pidx = l15 * 72 + tt * 16 + l4 * 4;
            *(uint2*)&Ph_s[w][pidx] = uint2{(unsigned)phv[0] | ((unsigned)phv[1] << 16),
                                            (unsigned)phv[2] | ((unsigned)phv[3] << 16)};
            *(uint2*)&Pl_s[w][pidx] = uint2{(unsigned)plv[0] | ((unsigned)plv[1] << 16),
                                            (unsigned)plv[2] | ((unsigned)plv[3] << 16)};
        }
        // same-wave RAW: compiler inserts lgkmcnt
#pragma unroll
        for (int kss = 0; kss < 2; ++kss) {
            int koff = kss * 32 + l4 * 8;
            f16x8 pbh = *(const f16x8*)&Ph_s[w][l15 * 72 + koff];
            f16x8 pbl = *(const f16x8*)&Pl_s[w][l15 * 72 + koff];
            int K0 = half * 64 + kss * 32 + l4 * 8;   // window-local key base
            int kk = K0 ^ (l15 << 3);                 // (d&15)==l15 for d=dt*16+l15
#pragma unroll
            for (int dt = 0; dt < 4; ++dt) {
                int d = dt * 16 + l15;
                f16x8 vh = *(const f16x8*)&VTh[d * 128 + kk];
                f16x8 vl = *(const f16x8*)&VTl[d * 128 + kk];
                o[dt] = MFMA(vh, pbh, o[dt]);
                o[dt] = MFMA(vh, pbl, o[dt]);
                o[dt] = MFMA(vl, pbh, o[dt]);
            }
        }
    }

    // ---- epilogue: O^T/lsum -> GEMM2-A hi plane (swizzled)
    float inv = 1.0f / lsum;
    const int srow = qrow;
#pragma unroll
    for (int dt = 0; dt < 4; ++dt) {
        u16 hv[4];
#pragma unroll
        for (int j = 0; j < 4; ++j) hv[j] = f2h(o[dt][j] * inv);
        int col0 = h * 64 + dt * 16 + l4 * 4;
        size_t di = (size_t)srow * 768 + (col0 >> 5) * 32
                  + (size_t)((((col0 >> 3) & 3) ^ (srow & 3))) * 8 + (col0 & 7);
        *(uint2*)(OAh + di) = uint2{(unsigned)hv[0] | ((unsigned)hv[1] << 16),
                                    (unsigned)hv[2] | ((unsigned)hv[3] << 16)};
    }
}

extern "C" void kernel_launch(void* const* d_in, const int* in_sizes, int n_in,
                              void* d_out, int out_size, void* d_ws, size_t ws_size,
                              hipStream_t stream)
{
    const float* hs   = (const float*)d_in[0];
    const float* wqkv = (const float*)d_in[1];
    const float* wo   = (const float*)d_in[2];
    const float* cosT = (const float*)d_in[3];
    const float* sinT = (const float*)d_in[4];
    // d_in[5] attention_mask: unused (mask applied analytically)
    float* out = (float*)d_out;

    char* p = (char*)d_ws;
    unsigned* qkvP = (unsigned*)p;      p += (size_t)3 * NHEADS * SLEN * HEADD * 4;  // 37.75 MB
    u16* hsH = (u16*)p;                 p += (size_t)SLEN * HDIM * 2;                // 6.29 MB
    p += (size_t)SLEN * HDIM * 2;       // (reserved; lo plane of hs/attn-out unused)
    u16* wqH = (u16*)p;                 p += (size_t)NQKV * HDIM * 2;                // 3.54 MB
    u16* wqL = (u16*)p;                 p += (size_t)NQKV * HDIM * 2;
    u16* woH = (u16*)p;                 p += (size_t)HDIM * HDIM * 2;                // 1.18 MB
    u16* woL = (u16*)p;                 p += (size_t)HDIM * HDIM * 2;
    // attention output hi-plane aliases hs hi-plane (hs only read by GEMM1)
    u16* oAh = hsH;

    split_planes<<<2688, 256, 0, stream>>>(hs, wqkv, wo, hsH, wqH, wqL, woH, woL);

    // GEMM1: 128x128 tiles, 1D grid 576 = 18 cols x 32 rows (576 % 8 == 0)
    gemm_sp<128, 1><<<576, 256, 0, stream>>>(hsH, wqH, wqL, qkvP,
                                             NQKV, HDIM, cosT, sinT, 18);

    attn_mfma<<<NHEADS * (SLEN / 64), 256, 0, stream>>>(qkvP, oAh);

    // GEMM2: 64x128 tiles, 1D grid 384 = 6 cols x 64 rows (384 % 8 == 0)
    gemm_sp<64, 0><<<384, 256, 0, stream>>>(oAh, woH, woL, out,
                                            HDIM, HDIM, nullptr, nullptr, 6);
}